// Round 13
// baseline (118.225 us; speedup 1.0000x reference)
//
#include <hip/hip_runtime.h>
#include <hip/hip_bf16.h>
#include <stdint.h>

#define NHEADS 12
#define HSZ 64
#define BATCH 8
#define SEQ 1024
#define DIN 1024
#define NPROJ 1536   // NHEADS*HSZ*2
#define MTOK 8192    // BATCH*SEQ
#define NEGV 1e12f

typedef float  f32x4  __attribute__((ext_vector_type(4)));
typedef __bf16 bf16x8 __attribute__((ext_vector_type(8)));

__device__ __forceinline__ ushort f2bf(float x) {
  union { float f; uint32_t u; } v; v.f = x;
  uint32_t r = v.u + 0x7FFFu + ((v.u >> 16) & 1u);
  return (ushort)(r >> 16);
}

__device__ __forceinline__ void async16(const void* g, void* l) {
  __builtin_amdgcn_global_load_lds(
      (const __attribute__((address_space(1))) uint32_t*)g,
      (__attribute__((address_space(3))) uint32_t*)l,
      16, 0, 0);
}

// ---------------- merged prep kernel ----------------
__global__ __launch_bounds__(256) void k_prep(
    const float* __restrict__ inp, const float* __restrict__ W,
    ushort* __restrict__ A16, ushort* __restrict__ Wt, float* __restrict__ tab) {
  const int blk = blockIdx.x;
  const int tid = threadIdx.x;
  if (blk < 2048) {
    const float4* in4 = (const float4*)inp;
    ushort4* out4 = (ushort4*)A16;
    const int n4 = MTOK * DIN / 4;
    int i = blk * 256 + tid;
    for (; i < n4; i += 2048 * 256) {
      float4 v = in4[i];
      ushort4 o;
      o.x = f2bf(v.x); o.y = f2bf(v.y); o.z = f2bf(v.z); o.w = f2bf(v.w);
      out4[i] = o;
    }
  } else if (blk < 2432) {
    __shared__ float tile[64][65];
    const int bb = blk - 2048;           // 384 = 24 x 16
    const int n0 = (bb % 24) * 64;
    const int k0 = (bb / 24) * 64;
    const int c  = tid & 63;
    const int r0 = (tid >> 6) * 16;
    #pragma unroll
    for (int rr = 0; rr < 16; ++rr)
      tile[r0 + rr][c] = W[(size_t)(k0 + r0 + rr) * NPROJ + n0 + c];
    __syncthreads();
    #pragma unroll
    for (int rr = 0; rr < 16; ++rr)
      Wt[(size_t)(n0 + r0 + rr) * DIN + k0 + c] = f2bf(tile[c][r0 + rr]);
  } else {
    const int t = (blk - 2432) * 256 + tid;  // 32768 total
    const int s = t >> 5, i = t & 31;
    const float p   = powf(10000.0f, (float)i / 32.0f);
    const float ang = (float)s / p;
    tab[2 * t]     = sinf(ang);
    tab[2 * t + 1] = cosf(ang);
  }
}

// ------- projection GEMM + RoPE: BM=128 x BN=384, BK=32, 512 thr, 3-deep vmcnt -------
// r12 theory revision: proj was staging-BW-bound (402 MB staged). BN=384 cuts
// staged traffic to 259 MB and doubles compute per staged byte. Grid = 256
// blocks = exactly 1/CU; 96 KB LDS (3 buf x 32 KB); 8 waves (2m x 4n, 64x96 each).
// Per stage: every thread issues exactly 4 async16 -> vmcnt discipline = r12's.
__global__ __launch_bounds__(512, 2) void k_gemm_proj(
    const ushort* __restrict__ A, const ushort* __restrict__ Bt,
    const float* __restrict__ bias, const float* __restrict__ tab,
    ushort* __restrict__ Qb, ushort* __restrict__ Kb) {
  __shared__ __align__(16) ushort As[3][128 * 32];   // 3 x 8 KB
  __shared__ __align__(16) ushort Bs[3][384 * 32];   // 3 x 24 KB
  const int tid  = threadIdx.x;
  const int lane = tid & 63;
  const int wid  = tid >> 6;          // 0..7
  const int wm = wid >> 2, wn = wid & 3;   // 2 x 4 wave grid
  // XCD-aware remap (bijective: 256 % 8 == 0): each XCD owns 8 m-tiles x 4 n-tiles
  const int orig  = blockIdx.x;
  const int local = orig >> 3;        // 0..31
  const int mt = (orig & 7) * 8 + (local >> 2);  // 0..63
  const int nt = local & 3;                      // 0..3
  const int m0 = mt * 128;
  const int n0 = nt * 384;

  // staging: linear LDS rows of 64 B (32 bf16) = 4 x 16B slots.
  // swizzle involution: slot_lds = slot_g ^ ((row>>1)&3), applied to SOURCE.
  // A: issue 0, rows tid>>2 (0..127), slot tid&3.
  // B: issues 1..3, rows tid>>2 + (is-1)*128 (0..383), slot tid&3.
  const int rA  = tid >> 2;
  const int sl  = tid & 3;
  const int gA8 = (sl ^ ((rA >> 1) & 3)) * 8;
  const ushort* gA = A + (size_t)(m0 + rA) * DIN + gA8;
  const ushort* gB[3];
  #pragma unroll
  for (int is = 0; is < 3; ++is) {
    const int rB = rA + is * 128;
    const int gB8 = (sl ^ ((rB >> 1) & 3)) * 8;
    gB[is] = Bt + (size_t)(n0 + rB) * DIN + gB8;
  }
  const int ldsA = wid * 512;                 // ushort units (wave base; HW adds lane*16B)
  int ldsB[3];
  #pragma unroll
  for (int is = 0; is < 3; ++is) ldsB[is] = is * 4096 + wid * 512;

  // fragment read offsets (ushort units), same swizzle on READ side
  const int kb = lane >> 4;
  int aoff[4], boff[6];
  #pragma unroll
  for (int i = 0; i < 4; ++i) {
    const int ra = wm * 64 + i * 16 + (lane & 15);
    aoff[i] = ra * 32 + (kb ^ ((ra >> 1) & 3)) * 8;
  }
  #pragma unroll
  for (int i = 0; i < 6; ++i) {
    const int rb = wn * 96 + i * 16 + (lane & 15);
    boff[i] = rb * 32 + (kb ^ ((rb >> 1) & 3)) * 8;
  }

  ushort *a0 = As[0], *a1 = As[1], *a2 = As[2];
  ushort *b0 = Bs[0], *b1 = Bs[1], *b2 = Bs[2];

  f32x4 acc[4][6] = {};
  // prologue: stage tiles 0,1 (4 vmcnt events each per thread)
  async16(gA, a0 + ldsA);
  async16(gB[0], b0 + ldsB[0]); async16(gB[1], b0 + ldsB[1]); async16(gB[2], b0 + ldsB[2]);
  async16(gA + 32, a1 + ldsA);
  async16(gB[0] + 32, b1 + ldsB[0]); async16(gB[1] + 32, b1 + ldsB[1]); async16(gB[2] + 32, b1 + ldsB[2]);

  for (int kt = 0; kt < 31; ++kt) {
    asm volatile("s_waitcnt vmcnt(4)" ::: "memory");  // stage(kt) landed
    __builtin_amdgcn_s_barrier();                     // no full drain
    if (kt < 30) {                                    // stage(kt+2)
      const int ko = (kt + 2) * 32;
      async16(gA + ko, a2 + ldsA);
      async16(gB[0] + ko, b2 + ldsB[0]);
      async16(gB[1] + ko, b2 + ldsB[1]);
      async16(gB[2] + ko, b2 + ldsB[2]);
    }
    bf16x8 af[4], bfr[6];
    #pragma unroll
    for (int i = 0; i < 4; ++i) af[i]  = *(const bf16x8*)(a0 + aoff[i]);
    #pragma unroll
    for (int i = 0; i < 6; ++i) bfr[i] = *(const bf16x8*)(b0 + boff[i]);
    #pragma unroll
    for (int mi = 0; mi < 4; ++mi)
      #pragma unroll
      for (int ni = 0; ni < 6; ++ni)
        acc[mi][ni] = __builtin_amdgcn_mfma_f32_16x16x32_bf16(af[mi], bfr[ni], acc[mi][ni], 0, 0, 0);
    ushort* ta = a0; a0 = a1; a1 = a2; a2 = ta;
    ushort* tb = b0; b0 = b1; b1 = b2; b2 = tb;
  }
  asm volatile("s_waitcnt vmcnt(0)" ::: "memory");
  __builtin_amdgcn_s_barrier();
  {
    bf16x8 af[4], bfr[6];
    #pragma unroll
    for (int i = 0; i < 4; ++i) af[i]  = *(const bf16x8*)(a0 + aoff[i]);
    #pragma unroll
    for (int i = 0; i < 6; ++i) bfr[i] = *(const bf16x8*)(b0 + boff[i]);
    #pragma unroll
    for (int mi = 0; mi < 4; ++mi)
      #pragma unroll
      for (int ni = 0; ni < 6; ++ni)
        acc[mi][ni] = __builtin_amdgcn_mfma_f32_16x16x32_bf16(af[mi], bfr[ni], acc[mi][ni], 0, 0, 0);
  }

  // epilogue: bias + RoPE + scatter to Q/K (bf16)
  const int b = m0 >> 10;  // 128-row m-tile never crosses a batch boundary
  const int baserow = m0 + wm * 64 + ((lane >> 4) << 2);
  #pragma unroll
  for (int ni = 0; ni < 6; ++ni) {
    const int n = n0 + wn * 96 + ni * 16 + (lane & 15);   // n parity == lane parity
    const float bv = bias[n];
    const int h  = n >> 7;
    const int c  = n & 127;
    const int d  = c & 63;
    const int pi = d >> 1;
    ushort* dst = ((c < 64) ? Qb : Kb) + (size_t)(b * NHEADS + h) * SEQ * 64 + d;
    #pragma unroll
    for (int mi = 0; mi < 4; ++mi) {
      #pragma unroll
      for (int j = 0; j < 4; ++j) {
        const int gm = baserow + mi * 16 + j;
        const int s  = gm & (SEQ - 1);
        float v = acc[mi][ni][j] + bv;
        float p = __shfl_xor(v, 1);  // paired channel (n^1) lives in lane^1
        float2 sc = ((const float2*)tab)[s * 32 + pi];
        float o = (d & 1) ? fmaf(v, sc.y, p * sc.x) : fmaf(v, sc.y, -p * sc.x);
        dst[(size_t)s * 64] = f2bf(o);
      }
    }
  }
}

// ---------------- output: all 64 tiles per bh (r10-proven, unchanged) ----------------
__global__ __launch_bounds__(256) void k_out(
    const ushort* __restrict__ Qb, const ushort* __restrict__ Kb,
    const int* __restrict__ mask, float* __restrict__ out) {
  __shared__ __align__(16) ushort Qs[128 * 64];
  __shared__ __align__(16) ushort Ks[128 * 64];
  const int tid  = threadIdx.x;
  // XCD-aware remap (bijective: 6144 % 8 == 0; 768 wgid per XCD = 12 bh)
  const int orig = blockIdx.x;
  const int wgid = (orig & 7) * 768 + (orig >> 3);
  const int bh = wgid >> 6;              // 0..95
  const int b  = bh / NHEADS;
  const int mi_ = (wgid >> 3) & 7;
  const int ni_ = wgid & 7;
  const int m0 = mi_ * 128;
  const int n0 = ni_ * 128;
  const int* mb = mask + b * SEQ;
  float* ob = out + (size_t)bh * SEQ * SEQ;

  if (mi_ > ni_) {
    // ---- causal fill path: coalesced f32x4 nt streaming write ----
    const int c0 = (tid & 31) * 4;
    const int r0 = tid >> 5;
    f32x4 np4;
    #pragma unroll
    for (int j = 0; j < 4; ++j) np4[j] = mb[n0 + c0 + j] ? 0.0f : NEGV;
    for (int r = r0; r < 128; r += 8) {
      const int gm = m0 + r;
      const float mp = (mb[gm] ? 0.0f : NEGV) + NEGV;
      f32x4 v;
      #pragma unroll
      for (int j = 0; j < 4; ++j) v[j] = -(np4[j] + mp) * 0.125f;
      __builtin_nontemporal_store(v, (f32x4*)(ob + (size_t)gm * SEQ + n0 + c0));
    }
    return;
  }

  // ---- MFMA path (plain stores; r9: scalar nt stores are 2x slower) ----
  const int lane = tid & 63;
  const int wid  = tid >> 6;
  const int wm = wid >> 1, wn = wid & 1;
  const ushort* Qt = Qb + (size_t)bh * SEQ * 64;
  const ushort* Kt = Kb + (size_t)bh * SEQ * 64;

  #pragma unroll
  for (int is = 0; is < 4; ++is) {
    const int off = is * 4096 + tid * 16;
    const int row = off >> 7;
    const int g8  = ((((off >> 4) & 7) ^ (row & 7))) * 8;
    async16(Qt + (size_t)(m0 + row) * 64 + g8, Qs + is * 2048 + wid * 512);
    async16(Kt + (size_t)(n0 + row) * 64 + g8, Ks + is * 2048 + wid * 512);
  }
  __syncthreads();

  f32x4 acc[4][4] = {};
  const int kb = lane >> 4;
  #pragma unroll
  for (int ks = 0; ks < 2; ++ks) {
    bf16x8 qf[4], kf[4];
    #pragma unroll
    for (int i = 0; i < 4; ++i) {
      const int rq = wm * 64 + i * 16 + (lane & 15);
      qf[i] = *(const bf16x8*)(Qs + rq * 64 + ((ks * 4 + kb) ^ (rq & 7)) * 8);
      const int rk = wn * 64 + i * 16 + (lane & 15);
      kf[i] = *(const bf16x8*)(Ks + rk * 64 + ((ks * 4 + kb) ^ (rk & 7)) * 8);
    }
    #pragma unroll
    for (int mi = 0; mi < 4; ++mi)
      #pragma unroll
      for (int ni = 0; ni < 4; ++ni)
        acc[mi][ni] = __builtin_amdgcn_mfma_f32_16x16x32_bf16(qf[mi], kf[ni], acc[mi][ni], 0, 0, 0);
  }

  const int mrow0 = m0 + wm * 64 + ((lane >> 4) << 2);
  const int ncol0 = n0 + wn * 64 + (lane & 15);
  float npen[4];
  int gn_[4];
  #pragma unroll
  for (int ni = 0; ni < 4; ++ni) {
    gn_[ni]  = ncol0 + ni * 16;
    npen[ni] = mb[gn_[ni]] ? 0.0f : NEGV;
  }
  #pragma unroll
  for (int mi = 0; mi < 4; ++mi) {
    #pragma unroll
    for (int j = 0; j < 4; ++j) {
      const int gm = mrow0 + mi * 16 + j;
      const float mpen = mb[gm] ? 0.0f : NEGV;
      float* orow = ob + (size_t)gm * SEQ;
      #pragma unroll
      for (int ni = 0; ni < 4; ++ni) {
        const int gn = gn_[ni];
        const float tpen = (gm > gn) ? NEGV : 0.0f;
        orow[gn] = (acc[mi][ni][j] - (mpen + npen[ni] + tpen)) * 0.125f;
      }
    }
  }
}

// ---------------- launcher ----------------
extern "C" void kernel_launch(void* const* d_in, const int* in_sizes, int n_in,
                              void* d_out, int out_size, void* d_ws, size_t ws_size,
                              hipStream_t stream) {
  const float* inp  = (const float*)d_in[0];  // [8][1024][1024]
  const float* W    = (const float*)d_in[1];  // [1024][1536]
  const float* bias = (const float*)d_in[2];  // [1536]
  const int*   mask = (const int*)d_in[3];    // [8][1024]
  float* out = (float*)d_out;                 // [8][12][1024][1024]

  char* ws = (char*)d_ws;
  ushort* A16  = (ushort*)ws;                 // 16,777,216 B
  ushort* WT16 = (ushort*)(ws + 16777216);    //  3,145,728 B
  float*  tab  = (float*)(ws + 19922944);     //    262,144 B
  ushort* Qb   = (ushort*)(ws + 20185088);    // 12,582,912 B
  ushort* Kb   = (ushort*)(ws + 32768000);    // 12,582,912 B  (total ~45.4 MB)

  k_prep<<<2560, 256, 0, stream>>>(inp, W, A16, WT16, tab);
  k_gemm_proj<<<256, 512, 0, stream>>>(A16, WT16, bias, tab, Qb, Kb);
  k_out<<<6144, 256, 0, stream>>>(Qb, Kb, mask, out);
}

// Round 14
// 112.457 us; speedup vs baseline: 1.0513x; 1.0513x over previous
//
#include <hip/hip_runtime.h>
#include <hip/hip_bf16.h>
#include <stdint.h>

#define NHEADS 12
#define HSZ 64
#define BATCH 8
#define SEQ 1024
#define DIN 1024
#define NPROJ 1536   // NHEADS*HSZ*2
#define MTOK 8192    // BATCH*SEQ
#define NEGV 1e12f

typedef float  f32x4  __attribute__((ext_vector_type(4)));
typedef __bf16 bf16x8 __attribute__((ext_vector_type(8)));

__device__ __forceinline__ ushort f2bf(float x) {
  union { float f; uint32_t u; } v; v.f = x;
  uint32_t r = v.u + 0x7FFFu + ((v.u >> 16) & 1u);
  return (ushort)(r >> 16);
}

__device__ __forceinline__ void async16(const void* g, void* l) {
  __builtin_amdgcn_global_load_lds(
      (const __attribute__((address_space(1))) uint32_t*)g,
      (__attribute__((address_space(3))) uint32_t*)l,
      16, 0, 0);
}

// ---------------- merged prep kernel ----------------
__global__ __launch_bounds__(256) void k_prep(
    const float* __restrict__ inp, const float* __restrict__ W,
    ushort* __restrict__ A16, ushort* __restrict__ Wt, float* __restrict__ tab) {
  const int blk = blockIdx.x;
  const int tid = threadIdx.x;
  if (blk < 2048) {
    const float4* in4 = (const float4*)inp;
    ushort4* out4 = (ushort4*)A16;
    const int n4 = MTOK * DIN / 4;
    int i = blk * 256 + tid;
    for (; i < n4; i += 2048 * 256) {
      float4 v = in4[i];
      ushort4 o;
      o.x = f2bf(v.x); o.y = f2bf(v.y); o.z = f2bf(v.z); o.w = f2bf(v.w);
      out4[i] = o;
    }
  } else if (blk < 2432) {
    __shared__ float tile[64][65];
    const int bb = blk - 2048;           // 384 = 24 x 16
    const int n0 = (bb % 24) * 64;
    const int k0 = (bb / 24) * 64;
    const int c  = tid & 63;
    const int r0 = (tid >> 6) * 16;
    #pragma unroll
    for (int rr = 0; rr < 16; ++rr)
      tile[r0 + rr][c] = W[(size_t)(k0 + r0 + rr) * NPROJ + n0 + c];
    __syncthreads();
    #pragma unroll
    for (int rr = 0; rr < 16; ++rr)
      Wt[(size_t)(n0 + r0 + rr) * DIN + k0 + c] = f2bf(tile[c][r0 + rr]);
  } else {
    const int t = (blk - 2432) * 256 + tid;  // 32768 total
    const int s = t >> 5, i = t & 31;
    const float p   = powf(10000.0f, (float)i / 32.0f);
    const float ang = (float)s / p;
    tab[2 * t]     = sinf(ang);
    tab[2 * t + 1] = cosf(ang);
  }
}

// ------- projection GEMM + RoPE: BM=128 x BN=384, BK=32, 512 thr, 3-deep vmcnt,
//         LDS-bounce coalesced epilogue (new in r14) -------
__global__ __launch_bounds__(512, 2) void k_gemm_proj(
    const ushort* __restrict__ A, const ushort* __restrict__ Bt,
    const float* __restrict__ bias, const float* __restrict__ tab,
    ushort* __restrict__ Qb, ushort* __restrict__ Kb) {
  __shared__ __align__(16) ushort SH[49152];   // 96 KB: 3xA(8K) + 3xB(24K); reused by epilogue
  const int tid  = threadIdx.x;
  const int lane = tid & 63;
  const int wid  = tid >> 6;          // 0..7
  const int wm = wid >> 2, wn = wid & 3;   // 2 x 4 wave grid
  // XCD-aware remap (bijective: 256 % 8 == 0): each XCD owns 8 m-tiles x 4 n-tiles
  const int orig  = blockIdx.x;
  const int local = orig >> 3;        // 0..31
  const int mt = (orig & 7) * 8 + (local >> 2);  // 0..63
  const int nt = local & 3;                      // 0..3
  const int m0 = mt * 128;
  const int n0 = nt * 384;

  // staging: linear LDS rows of 64 B (32 bf16) = 4 x 16B slots.
  // swizzle involution: slot_lds = slot_g ^ ((row>>1)&3), applied to SOURCE.
  const int rA  = tid >> 2;
  const int sl  = tid & 3;
  const int gA8 = (sl ^ ((rA >> 1) & 3)) * 8;
  const ushort* gA = A + (size_t)(m0 + rA) * DIN + gA8;
  const ushort* gB[3];
  #pragma unroll
  for (int is = 0; is < 3; ++is) {
    const int rB = rA + is * 128;
    const int gB8 = (sl ^ ((rB >> 1) & 3)) * 8;
    gB[is] = Bt + (size_t)(n0 + rB) * DIN + gB8;
  }
  const int ldsA = wid * 512;                 // ushort units (wave base; HW adds lane*16B)
  int ldsB[3];
  #pragma unroll
  for (int is = 0; is < 3; ++is) ldsB[is] = is * 4096 + wid * 512;

  // fragment read offsets (ushort units), same swizzle on READ side
  const int kb = lane >> 4;
  int aoff[4], boff[6];
  #pragma unroll
  for (int i = 0; i < 4; ++i) {
    const int ra = wm * 64 + i * 16 + (lane & 15);
    aoff[i] = ra * 32 + (kb ^ ((ra >> 1) & 3)) * 8;
  }
  #pragma unroll
  for (int i = 0; i < 6; ++i) {
    const int rb = wn * 96 + i * 16 + (lane & 15);
    boff[i] = rb * 32 + (kb ^ ((rb >> 1) & 3)) * 8;
  }

  ushort *a0 = SH,         *a1 = SH + 4096,          *a2 = SH + 8192;
  ushort *b0 = SH + 12288, *b1 = SH + 12288 + 12288, *b2 = SH + 12288 + 24576;

  f32x4 acc[4][6] = {};
  // prologue: stage tiles 0,1 (4 vmcnt events each per thread)
  async16(gA, a0 + ldsA);
  async16(gB[0], b0 + ldsB[0]); async16(gB[1], b0 + ldsB[1]); async16(gB[2], b0 + ldsB[2]);
  async16(gA + 32, a1 + ldsA);
  async16(gB[0] + 32, b1 + ldsB[0]); async16(gB[1] + 32, b1 + ldsB[1]); async16(gB[2] + 32, b1 + ldsB[2]);

  for (int kt = 0; kt < 31; ++kt) {
    asm volatile("s_waitcnt vmcnt(4)" ::: "memory");  // stage(kt) landed
    __builtin_amdgcn_s_barrier();                     // no full drain
    if (kt < 30) {                                    // stage(kt+2)
      const int ko = (kt + 2) * 32;
      async16(gA + ko, a2 + ldsA);
      async16(gB[0] + ko, b2 + ldsB[0]);
      async16(gB[1] + ko, b2 + ldsB[1]);
      async16(gB[2] + ko, b2 + ldsB[2]);
    }
    bf16x8 af[4], bfr[6];
    #pragma unroll
    for (int i = 0; i < 4; ++i) af[i]  = *(const bf16x8*)(a0 + aoff[i]);
    #pragma unroll
    for (int i = 0; i < 6; ++i) bfr[i] = *(const bf16x8*)(b0 + boff[i]);
    #pragma unroll
    for (int mi = 0; mi < 4; ++mi)
      #pragma unroll
      for (int ni = 0; ni < 6; ++ni)
        acc[mi][ni] = __builtin_amdgcn_mfma_f32_16x16x32_bf16(af[mi], bfr[ni], acc[mi][ni], 0, 0, 0);
    ushort* ta = a0; a0 = a1; a1 = a2; a2 = ta;
    ushort* tb = b0; b0 = b1; b1 = b2; b2 = tb;
  }
  asm volatile("s_waitcnt vmcnt(0)" ::: "memory");
  __builtin_amdgcn_s_barrier();
  {
    bf16x8 af[4], bfr[6];
    #pragma unroll
    for (int i = 0; i < 4; ++i) af[i]  = *(const bf16x8*)(a0 + aoff[i]);
    #pragma unroll
    for (int i = 0; i < 6; ++i) bfr[i] = *(const bf16x8*)(b0 + boff[i]);
    #pragma unroll
    for (int mi = 0; mi < 4; ++mi)
      #pragma unroll
      for (int ni = 0; ni < 6; ++ni)
        acc[mi][ni] = __builtin_amdgcn_mfma_f32_16x16x32_bf16(af[mi], bfr[ni], acc[mi][ni], 0, 0, 0);
  }

  // ---- epilogue v2: RoPE in-reg -> bf16 -> LDS [128][384] (row-XOR swizzle)
  //      -> fully-coalesced 16B/lane global writes ----
  __syncthreads();   // all waves' staged-tile reads retired; SH is free
  const int b = m0 >> 10;  // 128-row m-tile never crosses a batch boundary
  const int rbase = wm * 64 + ((lane >> 4) << 2);
  #pragma unroll
  for (int ni = 0; ni < 6; ++ni) {
    const int col = wn * 96 + ni * 16 + (lane & 15);
    const int n   = n0 + col;
    const float bv = bias[n];
    const int pi = (n & 63) >> 1;
    #pragma unroll
    for (int mi = 0; mi < 4; ++mi) {
      #pragma unroll
      for (int j = 0; j < 4; ++j) {
        const int row = rbase + mi * 16 + j;
        const int s   = (m0 + row) & (SEQ - 1);
        float v = acc[mi][ni][j] + bv;
        float p = __shfl_xor(v, 1);  // paired channel (n^1) lives in lane^1
        float2 sc = ((const float2*)tab)[s * 32 + pi];
        float o = (n & 1) ? fmaf(v, sc.y, p * sc.x) : fmaf(v, sc.y, -p * sc.x);
        // XOR swizzle within each 64-elem half-head span (bits 3-5 of col)
        SH[row * 384 + (col ^ ((row & 7) << 3))] = f2bf(o);
      }
    }
  }
  __syncthreads();
  // copy: 12 sweeps x 512 threads x 16 B; 8 consecutive threads = one 128 B
  // (s, head, Q/K-half) row -> wave writes 1 KB contiguous per instruction.
  #pragma unroll
  for (int it = 0; it < 12; ++it) {
    const int idx = it * 512 + tid;
    const int d8  = idx & 7;
    const int rh  = idx >> 3;        // 0..767
    const int row = rh & 127;
    const int hh  = rh >> 7;         // 0..5 half-head within the 384-col span
    const int col = hh * 64 + d8 * 8;
    bf16x8 val = *(const bf16x8*)(SH + row * 384 + (col ^ ((row & 7) << 3)));
    const int h = nt * 3 + (hh >> 1);
    const int s = (m0 + row) & (SEQ - 1);
    ushort* dst = ((hh & 1) ? Kb : Qb) + ((size_t)(b * NHEADS + h) * SEQ + s) * 64 + d8 * 8;
    *(bf16x8*)dst = val;
  }
}

// ---------------- output: all 64 tiles per bh (r10-proven, unchanged) ----------------
__global__ __launch_bounds__(256) void k_out(
    const ushort* __restrict__ Qb, const ushort* __restrict__ Kb,
    const int* __restrict__ mask, float* __restrict__ out) {
  __shared__ __align__(16) ushort Qs[128 * 64];
  __shared__ __align__(16) ushort Ks[128 * 64];
  const int tid  = threadIdx.x;
  // XCD-aware remap (bijective: 6144 % 8 == 0; 768 wgid per XCD = 12 bh)
  const int orig = blockIdx.x;
  const int wgid = (orig & 7) * 768 + (orig >> 3);
  const int bh = wgid >> 6;              // 0..95
  const int b  = bh / NHEADS;
  const int mi_ = (wgid >> 3) & 7;
  const int ni_ = wgid & 7;
  const int m0 = mi_ * 128;
  const int n0 = ni_ * 128;
  const int* mb = mask + b * SEQ;
  float* ob = out + (size_t)bh * SEQ * SEQ;

  if (mi_ > ni_) {
    // ---- causal fill path: coalesced f32x4 nt streaming write ----
    const int c0 = (tid & 31) * 4;
    const int r0 = tid >> 5;
    f32x4 np4;
    #pragma unroll
    for (int j = 0; j < 4; ++j) np4[j] = mb[n0 + c0 + j] ? 0.0f : NEGV;
    for (int r = r0; r < 128; r += 8) {
      const int gm = m0 + r;
      const float mp = (mb[gm] ? 0.0f : NEGV) + NEGV;
      f32x4 v;
      #pragma unroll
      for (int j = 0; j < 4; ++j) v[j] = -(np4[j] + mp) * 0.125f;
      __builtin_nontemporal_store(v, (f32x4*)(ob + (size_t)gm * SEQ + n0 + c0));
    }
    return;
  }

  // ---- MFMA path (plain stores; r9: scalar nt stores are 2x slower) ----
  const int lane = tid & 63;
  const int wid  = tid >> 6;
  const int wm = wid >> 1, wn = wid & 1;
  const ushort* Qt = Qb + (size_t)bh * SEQ * 64;
  const ushort* Kt = Kb + (size_t)bh * SEQ * 64;

  #pragma unroll
  for (int is = 0; is < 4; ++is) {
    const int off = is * 4096 + tid * 16;
    const int row = off >> 7;
    const int g8  = ((((off >> 4) & 7) ^ (row & 7))) * 8;
    async16(Qt + (size_t)(m0 + row) * 64 + g8, Qs + is * 2048 + wid * 512);
    async16(Kt + (size_t)(n0 + row) * 64 + g8, Ks + is * 2048 + wid * 512);
  }
  __syncthreads();

  f32x4 acc[4][4] = {};
  const int kb = lane >> 4;
  #pragma unroll
  for (int ks = 0; ks < 2; ++ks) {
    bf16x8 qf[4], kf[4];
    #pragma unroll
    for (int i = 0; i < 4; ++i) {
      const int rq = wm * 64 + i * 16 + (lane & 15);
      qf[i] = *(const bf16x8*)(Qs + rq * 64 + ((ks * 4 + kb) ^ (rq & 7)) * 8);
      const int rk = wn * 64 + i * 16 + (lane & 15);
      kf[i] = *(const bf16x8*)(Ks + rk * 64 + ((ks * 4 + kb) ^ (rk & 7)) * 8);
    }
    #pragma unroll
    for (int mi = 0; mi < 4; ++mi)
      #pragma unroll
      for (int ni = 0; ni < 4; ++ni)
        acc[mi][ni] = __builtin_amdgcn_mfma_f32_16x16x32_bf16(qf[mi], kf[ni], acc[mi][ni], 0, 0, 0);
  }

  const int mrow0 = m0 + wm * 64 + ((lane >> 4) << 2);
  const int ncol0 = n0 + wn * 64 + (lane & 15);
  float npen[4];
  int gn_[4];
  #pragma unroll
  for (int ni = 0; ni < 4; ++ni) {
    gn_[ni]  = ncol0 + ni * 16;
    npen[ni] = mb[gn_[ni]] ? 0.0f : NEGV;
  }
  #pragma unroll
  for (int mi = 0; mi < 4; ++mi) {
    #pragma unroll
    for (int j = 0; j < 4; ++j) {
      const int gm = mrow0 + mi * 16 + j;
      const float mpen = mb[gm] ? 0.0f : NEGV;
      float* orow = ob + (size_t)gm * SEQ;
      #pragma unroll
      for (int ni = 0; ni < 4; ++ni) {
        const int gn = gn_[ni];
        const float tpen = (gm > gn) ? NEGV : 0.0f;
        orow[gn] = (acc[mi][ni][j] - (mpen + npen[ni] + tpen)) * 0.125f;
      }
    }
  }
}

// ---------------- launcher ----------------
extern "C" void kernel_launch(void* const* d_in, const int* in_sizes, int n_in,
                              void* d_out, int out_size, void* d_ws, size_t ws_size,
                              hipStream_t stream) {
  const float* inp  = (const float*)d_in[0];  // [8][1024][1024]
  const float* W    = (const float*)d_in[1];  // [1024][1536]
  const float* bias = (const float*)d_in[2];  // [1536]
  const int*   mask = (const int*)d_in[3];    // [8][1024]
  float* out = (float*)d_out;                 // [8][12][1024][1024]

  char* ws = (char*)d_ws;
  ushort* A16  = (ushort*)ws;                 // 16,777,216 B
  ushort* WT16 = (ushort*)(ws + 16777216);    //  3,145,728 B
  float*  tab  = (float*)(ws + 19922944);     //    262,144 B
  ushort* Qb   = (ushort*)(ws + 20185088);    // 12,582,912 B
  ushort* Kb   = (ushort*)(ws + 32768000);    // 12,582,912 B  (total ~45.4 MB)

  k_prep<<<2560, 256, 0, stream>>>(inp, W, A16, WT16, tab);
  k_gemm_proj<<<256, 512, 0, stream>>>(A16, WT16, bias, tab, Qb, Kb);
  k_out<<<6144, 256, 0, stream>>>(Qb, Kb, mask, out);
}